// Round 1
// baseline (441.793 us; speedup 1.0000x reference)
//
#include <hip/hip_runtime.h>
#include <hip/hip_bf16.h>

#define DD 256
#define SCALAR 30.0f

typedef __attribute__((ext_vector_type(8))) short bf16x8;
typedef __attribute__((ext_vector_type(4))) float f32x4;

__device__ __forceinline__ unsigned short f2b(float f) {
    __hip_bfloat16 h = __float2bfloat16(f);
    return __builtin_bit_cast(unsigned short, h);
}

// K0: x = l2norm(inputs); store fp32 + bf16 copies; zero the loss accumulator.
__global__ void prep_kernel(const float* __restrict__ in, float* __restrict__ xf,
                            unsigned short* __restrict__ xb, float* __restrict__ out_loss) {
    int row = blockIdx.x, tid = threadIdx.x;
    __shared__ float red[256];
    float v = in[(size_t)row * DD + tid];
    red[tid] = v * v;
    __syncthreads();
    for (int h = 128; h > 0; h >>= 1) {
        if (tid < h) red[tid] += red[tid + h];
        __syncthreads();
    }
    float nrm = fmaxf(sqrtf(red[0]), 1e-12f);
    float xn = v / nrm;
    xf[(size_t)row * DD + tid] = xn;
    xb[(size_t)row * DD + tid] = f2b(xn);
    if (row == 0 && tid == 0) out_loss[0] = 0.f;
}

// K1: copy lut/cq -> outputs, compute empty-row flags. One wave per row.
__global__ void copy_flag_kernel(const float* __restrict__ lut, const float* __restrict__ cq,
                                 float* __restrict__ out_lut, float* __restrict__ out_cq,
                                 unsigned char* __restrict__ flags, int P, int R) {
    int wid = blockIdx.x * (blockDim.x >> 6) + (threadIdx.x >> 6);
    int lane = threadIdx.x & 63;
    int nw = gridDim.x * (blockDim.x >> 6);
    for (int r = wid; r < R; r += nw) {
        const float* src; float* dst;
        if (r < P) { src = lut + (size_t)r * DD; dst = out_lut + (size_t)r * DD; }
        else       { src = cq + (size_t)(r - P) * DD; dst = out_cq + (size_t)(r - P) * DD; }
        float4 v = *(const float4*)(src + lane * 4);
        // out region is offset by 1 float (loss scalar) -> 16B-misaligned: scalar stores (L2 merges)
        dst[lane*4+0] = v.x; dst[lane*4+1] = v.y; dst[lane*4+2] = v.z; dst[lane*4+3] = v.w;
        bool nz = (v.x != 0.f) || (v.y != 0.f) || (v.z != 0.f) || (v.w != 0.f);
        unsigned long long b = __ballot(nz);
        if (lane == 0) flags[r] = (b == 0ull) ? 1 : 0;
    }
}

// K2: bf16 MFMA GEMM tile (512 rows x 64 cols per block), per-row (max, sumexp) partials.
// Block: 8 waves; wave w owns rows [w*64, w*64+64), all 64 cols. K staged fully in LDS.
__global__ __launch_bounds__(512, 4) void gemm_lse_kernel(
    const unsigned short* __restrict__ xb, const float* __restrict__ lut,
    const float* __restrict__ cq, const unsigned char* __restrict__ flags,
    float* __restrict__ pm, float* __restrict__ ps, int N, int P, int C) {
    __shared__ unsigned short Bs[64][264];   // [col][k], pad 8 shorts: 528B stride, conflict-free b128 reads
    int tid = threadIdx.x;
    int w = tid >> 6, lane = tid & 63;
    int cb = blockIdx.x, rb = blockIdx.y;
    int col0 = cb * 64, row0 = rb * 512;

    // stage B tile: 64 cols x 256 k fp32 -> bf16 LDS (wave per col-row, coalesced 1KB reads)
    for (int it = 0; it < 8; ++it) {
        int c = it * 8 + w;
        int gc = col0 + c;
        float4 v = make_float4(0.f, 0.f, 0.f, 0.f);
        if (gc < C) {
            const float* src = (gc < P) ? (lut + (size_t)gc * DD) : (cq + (size_t)(gc - P) * DD);
            v = *(const float4*)(src + lane * 4);
        }
        unsigned short* d = &Bs[c][lane * 4];
        d[0] = f2b(v.x); d[1] = f2b(v.y); d[2] = f2b(v.z); d[3] = f2b(v.w);
    }
    __syncthreads();

    f32x4 acc[4][4];
    #pragma unroll
    for (int f = 0; f < 4; ++f)
        #pragma unroll
        for (int g = 0; g < 4; ++g) acc[f][g] = (f32x4){0.f, 0.f, 0.f, 0.f};

    int l15 = lane & 15, lg = lane >> 4;
    const unsigned short* aptr = xb + (size_t)(row0 + w * 64 + l15) * DD + lg * 8;

    for (int k0 = 0; k0 < DD; k0 += 32) {
        bf16x8 b[4];
        #pragma unroll
        for (int g = 0; g < 4; ++g)
            b[g] = *(const bf16x8*)&Bs[g * 16 + l15][k0 + lg * 8];
        #pragma unroll
        for (int f = 0; f < 4; ++f) {
            bf16x8 a = *(const bf16x8*)(aptr + f * 16 * DD + k0);
            #pragma unroll
            for (int g = 0; g < 4; ++g)
                acc[f][g] = __builtin_amdgcn_mfma_f32_16x16x32_bf16(a, b[g], acc[f][g], 0, 0, 0);
        }
    }

    // epilogue: mask -> per-row max/sumexp over this 64-col stripe
    bool validg[4], badg[4];
    #pragma unroll
    for (int g = 0; g < 4; ++g) {
        int col = col0 + g * 16 + l15;
        validg[g] = col < C;
        badg[g] = validg[g] && (flags[col] != 0);
    }
    #pragma unroll
    for (int f = 0; f < 4; ++f) {
        #pragma unroll
        for (int r = 0; r < 4; ++r) {
            float vv[4];
            #pragma unroll
            for (int g = 0; g < 4; ++g) {
                float d = SCALAR * acc[f][g][r];
                vv[g] = validg[g] ? (badg[g] ? -SCALAR : d) : -1e30f;
            }
            float m = fmaxf(fmaxf(vv[0], vv[1]), fmaxf(vv[2], vv[3]));
            #pragma unroll
            for (int off = 1; off < 16; off <<= 1) m = fmaxf(m, __shfl_xor(m, off));
            float s = expf(vv[0] - m) + expf(vv[1] - m) + expf(vv[2] - m) + expf(vv[3] - m);
            #pragma unroll
            for (int off = 1; off < 16; off <<= 1) s += __shfl_xor(s, off);
            if (l15 == 0) {
                int rloc = w * 64 + f * 16 + lg * 4 + r;   // D layout: row=(lane>>4)*4+reg
                size_t idx = (size_t)cb * N + row0 + rloc;
                pm[idx] = m;
                ps[idx] = s;
            }
        }
    }
}

// K3: per-row combine of CB partials -> lse; labeled logit in fp32; bad_pos correction; loss.
__global__ void finalize_kernel(const float* __restrict__ pm, const float* __restrict__ ps,
                                const float* __restrict__ xf, const float* __restrict__ lut,
                                const int* __restrict__ label, const unsigned char* __restrict__ flags,
                                float* __restrict__ out_loss, int CB, int N, int P) {
    int row = blockIdx.x, tid = threadIdx.x;
    int y = label[row];
    if (y >= P) return;   // unlabeled -> ce = 0 (uniform across block)
    __shared__ float sm[256], ss[256], sd[256];
    float m = -1e30f, s = 0.f;
    for (int cb = tid; cb < CB; cb += 256) {
        float bm = pm[(size_t)cb * N + row];
        float bs = ps[(size_t)cb * N + row];
        float M = fmaxf(m, bm);
        s = s * expf(m - M) + bs * expf(bm - M);
        m = M;
    }
    sm[tid] = m; ss[tid] = s;
    sd[tid] = xf[(size_t)row * DD + tid] * lut[(size_t)y * DD + tid];
    __syncthreads();
    for (int h = 128; h > 0; h >>= 1) {
        if (tid < h) {
            float m2 = sm[tid + h], s2 = ss[tid + h];
            float M = fmaxf(sm[tid], m2);
            ss[tid] = ss[tid] * expf(sm[tid] - M) + s2 * expf(m2 - M);
            sm[tid] = M;
            sd[tid] += sd[tid + h];
        }
        __syncthreads();
    }
    if (tid == 0) {
        float M = sm[0], S = ss[0];
        bool bad = flags[y] != 0;
        if (bad) S += expf(SCALAR - M) - expf(-SCALAR - M);  // own empty prototype: -30 -> +30
        float lse = M + logf(S);
        float llab = bad ? SCALAR : SCALAR * sd[0];
        atomicAdd(out_loss, (lse - llab) / (float)N);
    }
}

// K4: memory-bank update. One wave per sample; per-label sequential replay (pass1 then pass2).
__global__ __launch_bounds__(64) void update_kernel(
    const float* __restrict__ xf, const int* __restrict__ label,
    const float* __restrict__ ious, const float* __restrict__ lut,
    const int* __restrict__ header, float* __restrict__ out_lut,
    float* __restrict__ out_cq, int N, int P, int Q) {
    int i = blockIdx.x, lane = threadIdx.x;
    float s = 0.f;
    for (int j = lane; j < N; j += 64) s += ious[j];
    #pragma unroll
    for (int off = 32; off > 0; off >>= 1) s += __shfl_xor(s, off);
    if (s >= 0.2f * (float)N) return;   // ious.mean() >= 0.2 -> no update

    int y = label[i];
    if (y < P) {
        for (int j = 0; j < i; ++j) if (label[j] == y) return;  // only first occurrence drives
        float4 r = *(const float4*)(lut + (size_t)y * DD + lane * 4);
        for (int pass = 0; pass < 2; ++pass) {
            for (int j = i; j < N; ++j) {
                if (label[j] != y) continue;
                float b = (pass == 0) ? 0.5f : ious[j];
                float a = 1.f - b;
                float4 xj = *(const float4*)(xf + (size_t)j * DD + lane * 4);
                r.x = a * r.x + b * xj.x;
                r.y = a * r.y + b * xj.y;
                r.z = a * r.z + b * xj.z;
                r.w = a * r.w + b * xj.w;
                float ss2 = r.x * r.x + r.y * r.y + r.z * r.z + r.w * r.w;
                #pragma unroll
                for (int off = 32; off > 0; off >>= 1) ss2 += __shfl_xor(ss2, off);
                float inv = 1.f / fmaxf(sqrtf(ss2), 1e-12f);
                r.x *= inv; r.y *= inv; r.z *= inv; r.w *= inv;
            }
        }
        float* dst = out_lut + (size_t)y * DD + lane * 4;
        dst[0] = r.x; dst[1] = r.y; dst[2] = r.z; dst[3] = r.w;
    } else {
        // unlabeled: written twice into circular queue (once per scan pass)
        int rank = 0, U = 0;
        for (int j = 0; j < N; ++j) {
            bool u = (label[j] >= P);
            U += u ? 1 : 0;
            if (u && j < i) rank++;
        }
        int h0 = header[0];
        float4 xi = *(const float4*)(xf + (size_t)i * DD + lane * 4);
        long long p1 = ((long long)h0 + rank) % Q;
        long long p2 = ((long long)h0 + U + rank) % Q;
        float* d1 = out_cq + (size_t)p1 * DD + lane * 4;
        float* d2 = out_cq + (size_t)p2 * DD + lane * 4;
        d1[0] = xi.x; d1[1] = xi.y; d1[2] = xi.z; d1[3] = xi.w;
        d2[0] = xi.x; d2[1] = xi.y; d2[2] = xi.z; d2[3] = xi.w;
    }
}

extern "C" void kernel_launch(void* const* d_in, const int* in_sizes, int n_in,
                              void* d_out, int out_size, void* d_ws, size_t ws_size,
                              hipStream_t stream) {
    const float* inputs = (const float*)d_in[0];
    const int* label    = (const int*)d_in[1];
    const float* ious   = (const float*)d_in[2];
    const float* lut    = (const float*)d_in[3];
    const float* cq     = (const float*)d_in[4];
    const int* header   = (const int*)d_in[5];
    float* out = (float*)d_out;

    int N = in_sizes[0] / DD;      // 1024
    int P = in_sizes[3] / DD;      // 100000
    int Q = in_sizes[4] / DD;      // 50000
    int C = P + Q;                 // 150000
    int CB = (C + 63) / 64;        // 2344

    // workspace layout (~21 MB): xf | xb | pm | ps | flags
    char* ws = (char*)d_ws;
    float* xf = (float*)ws;
    unsigned short* xb = (unsigned short*)(ws + (size_t)N * DD * 4);
    float* pm = (float*)(ws + (size_t)N * DD * 6);
    float* ps = pm + (size_t)CB * N;
    unsigned char* flags = (unsigned char*)(ps + (size_t)CB * N);

    float* out_loss = out;
    float* out_lut  = out + 1;
    float* out_cq   = out + 1 + (size_t)P * DD;

    hipLaunchKernelGGL(prep_kernel, dim3(N), dim3(256), 0, stream, inputs, xf, xb, out_loss);
    hipLaunchKernelGGL(copy_flag_kernel, dim3(2048), dim3(256), 0, stream,
                       lut, cq, out_lut, out_cq, flags, P, C);
    hipLaunchKernelGGL(gemm_lse_kernel, dim3(CB, N / 512), dim3(512), 0, stream,
                       xb, lut, cq, flags, pm, ps, N, P, C);
    hipLaunchKernelGGL(finalize_kernel, dim3(N), dim3(256), 0, stream,
                       pm, ps, xf, lut, label, flags, out_loss, CB, N, P);
    hipLaunchKernelGGL(update_kernel, dim3(N), dim3(64), 0, stream,
                       xf, label, ious, lut, header, out_lut, out_cq, N, P, Q);
}

// Round 2
// 413.719 us; speedup vs baseline: 1.0679x; 1.0679x over previous
//
#include <hip/hip_runtime.h>
#include <hip/hip_bf16.h>

#define DD 256
#define SCALAR 30.0f
#define K2 43.28085122666891f     // 30 * log2(e)
#define LN2 0.6931471805599453f
#define CPB 256                   // columns per block (4 sub-tiles of 64)

typedef __attribute__((ext_vector_type(8))) short bf16x8;
typedef __attribute__((ext_vector_type(4))) float f32x4;

__device__ __forceinline__ float fexp2(float x) {
#if __has_builtin(__builtin_amdgcn_exp2f)
    return __builtin_amdgcn_exp2f(x);
#else
    return exp2f(x);
#endif
}

// RNE float->bf16 (no-NaN inputs)
__device__ __forceinline__ unsigned short f2b(float f) {
    unsigned int u = __builtin_bit_cast(unsigned int, f);
    u += 0x7FFFu + ((u >> 16) & 1u);
    return (unsigned short)(u >> 16);
}

// K0: x = l2norm(inputs); fp32 + bf16 copies; zero loss accumulator.
__global__ void prep_kernel(const float* __restrict__ in, float* __restrict__ xf,
                            unsigned short* __restrict__ xb, float* __restrict__ out_loss) {
    int row = blockIdx.x, tid = threadIdx.x;
    __shared__ float red[256];
    float v = in[(size_t)row * DD + tid];
    red[tid] = v * v;
    __syncthreads();
    for (int h = 128; h > 0; h >>= 1) {
        if (tid < h) red[tid] += red[tid + h];
        __syncthreads();
    }
    float nrm = fmaxf(sqrtf(red[0]), 1e-12f);
    float xn = v / nrm;
    xf[(size_t)row * DD + tid] = xn;
    xb[(size_t)row * DD + tid] = f2b(xn);
    if (row == 0 && tid == 0) out_loss[0] = 0.f;
}

// K1: fused GEMM + copy-out + per-row (max,sumexp) partials in log2 domain.
// Block: 8 waves x 512 rows x 256 cols (4 sub-tiles of 64 cols).
// Swapped MFMA operands: D col = x-row (lane&15), D row = C-column ((lane>>4)*4+reg).
__global__ __launch_bounds__(512, 3) void gemm_lse_kernel(
    const unsigned short* __restrict__ xb, const float* __restrict__ lut,
    const float* __restrict__ cq, float* __restrict__ out_lut, float* __restrict__ out_cq,
    float* __restrict__ pm, float* __restrict__ ps, int N, int P, int C) {
    __shared__ unsigned short Bs[64][264];   // [col][k], 528B stride
    int tid = threadIdx.x;
    int w = tid >> 6, lane = tid & 63;
    int l15 = lane & 15, lg = lane >> 4;
    int cb = blockIdx.x, rb = blockIdx.y;
    int row0 = rb * 512 + w * 64;

    float rm[4], rs[4];
    #pragma unroll
    for (int rf = 0; rf < 4; ++rf) { rm[rf] = -1e30f; rs[rf] = 0.f; }

    const unsigned short* aptr = xb + (size_t)(row0 + l15) * DD + lg * 8;

    for (int st = 0; st < 4; ++st) {
        int col00 = cb * CPB + st * 64;
        // stage B sub-tile (one column per wave per iter) + fused copy-out
        #pragma unroll
        for (int it = 0; it < 8; ++it) {
            int c = it * 8 + w;
            int gc = col00 + c;
            float4 v = make_float4(0.f, 0.f, 0.f, 0.f);
            if (gc < C) {
                const float* src = (gc < P) ? (lut + (size_t)gc * DD) : (cq + (size_t)(gc - P) * DD);
                v = *(const float4*)(src + lane * 4);
                if (rb == 0) {
                    // out region offset by 1 float (loss scalar): 4B-aligned scalar stores
                    float* dst = ((gc < P) ? (out_lut + (size_t)gc * DD)
                                           : (out_cq + (size_t)(gc - P) * DD)) + lane * 4;
                    dst[0] = v.x; dst[1] = v.y; dst[2] = v.z; dst[3] = v.w;
                }
            }
            unsigned short* d = &Bs[c][lane * 4];
            d[0] = f2b(v.x); d[1] = f2b(v.y); d[2] = f2b(v.z); d[3] = f2b(v.w);
        }
        __syncthreads();

        f32x4 acc[4][4];   // [cf][rf]
        #pragma unroll
        for (int cf = 0; cf < 4; ++cf)
            #pragma unroll
            for (int rf = 0; rf < 4; ++rf) acc[cf][rf] = (f32x4){0.f, 0.f, 0.f, 0.f};

        for (int k0 = 0; k0 < DD; k0 += 32) {
            bf16x8 b[4], a[4];
            #pragma unroll
            for (int cf = 0; cf < 4; ++cf)
                b[cf] = *(const bf16x8*)&Bs[cf * 16 + l15][k0 + lg * 8];
            #pragma unroll
            for (int rf = 0; rf < 4; ++rf)
                a[rf] = *(const bf16x8*)(aptr + rf * 16 * DD + k0);
            #pragma unroll
            for (int cf = 0; cf < 4; ++cf)
                #pragma unroll
                for (int rf = 0; rf < 4; ++rf)
                    acc[cf][rf] = __builtin_amdgcn_mfma_f32_16x16x32_bf16(b[cf], a[rf], acc[cf][rf], 0, 0, 0);
        }

        // per-lane online (max,sumexp) merge: each lane owns 16 cols for x-row l15
        #pragma unroll
        for (int rf = 0; rf < 4; ++rf) {
            float vv[16];
            float lm = -1e30f;
            #pragma unroll
            for (int cf = 0; cf < 4; ++cf)
                #pragma unroll
                for (int r = 0; r < 4; ++r) {
                    float v = K2 * acc[cf][rf][r];
                    vv[cf * 4 + r] = v;
                    lm = fmaxf(lm, v);
                }
            float ls = 0.f;
            #pragma unroll
            for (int t = 0; t < 16; ++t) ls += fexp2(vv[t] - lm);
            float M = fmaxf(rm[rf], lm);
            rs[rf] = rs[rf] * fexp2(rm[rf] - M) + ls * fexp2(lm - M);
            rm[rf] = M;
        }
        __syncthreads();
    }

    // cross-lane-group reduce (4 copies per x-row at lanes l15, l15+16, +32, +48)
    #pragma unroll
    for (int rf = 0; rf < 4; ++rf) {
        float m = rm[rf], s = rs[rf];
        float m1 = __shfl_xor(m, 16), s1 = __shfl_xor(s, 16);
        float M = fmaxf(m, m1);
        s = s * fexp2(m - M) + s1 * fexp2(m1 - M);
        m = M;
        m1 = __shfl_xor(m, 32); s1 = __shfl_xor(s, 32);
        M = fmaxf(m, m1);
        s = s * fexp2(m - M) + s1 * fexp2(m1 - M);
        if (lg == 0) {
            size_t idx = (size_t)cb * N + row0 + rf * 16 + l15;
            pm[idx] = M;
            ps[idx] = s;
        }
    }
}

// K2: per-row combine of CB partials -> lse (log2 domain); exact label logit; loss.
__global__ void finalize_kernel(const float* __restrict__ pm, const float* __restrict__ ps,
                                const float* __restrict__ xf, const float* __restrict__ lut,
                                const int* __restrict__ label, float* __restrict__ out_loss,
                                int CB, int N, int P) {
    int row = blockIdx.x, tid = threadIdx.x;
    int y = label[row];
    if (y >= P) return;   // unlabeled -> ce contribution 0
    __shared__ float sm[256], ss[256], sd[256];
    __shared__ int snz[256];
    float m = -1e30f, s = 0.f;
    for (int cb = tid; cb < CB; cb += 256) {
        float bm = pm[(size_t)cb * N + row];
        float bs = ps[(size_t)cb * N + row];
        float M = fmaxf(m, bm);
        s = s * fexp2(m - M) + bs * fexp2(bm - M);
        m = M;
    }
    float lv = lut[(size_t)y * DD + tid];
    sm[tid] = m; ss[tid] = s;
    sd[tid] = xf[(size_t)row * DD + tid] * lv;
    snz[tid] = (lv != 0.f) ? 1 : 0;
    __syncthreads();
    for (int h = 128; h > 0; h >>= 1) {
        if (tid < h) {
            float m2 = sm[tid + h], s2 = ss[tid + h];
            float M = fmaxf(sm[tid], m2);
            ss[tid] = ss[tid] * fexp2(sm[tid] - M) + s2 * fexp2(m2 - M);
            sm[tid] = M;
            sd[tid] += sd[tid + h];
            snz[tid] |= snz[tid + h];
        }
        __syncthreads();
    }
    if (tid == 0) {
        bool bad = (snz[0] == 0);          // own prototype empty -> logit forced to +30
        float lse = LN2 * (sm[0] + log2f(ss[0]));
        float llab = bad ? SCALAR : SCALAR * sd[0];
        atomicAdd(out_loss, (lse - llab) / (float)N);
    }
}

// K3: memory-bank update. One wave per sample; per-label sequential replay (pass1 then pass2).
__global__ __launch_bounds__(64) void update_kernel(
    const float* __restrict__ xf, const int* __restrict__ label,
    const float* __restrict__ ious, const float* __restrict__ lut,
    const int* __restrict__ header, float* __restrict__ out_lut,
    float* __restrict__ out_cq, int N, int P, int Q) {
    int i = blockIdx.x, lane = threadIdx.x;
    float s = 0.f;
    for (int j = lane; j < N; j += 64) s += ious[j];
    #pragma unroll
    for (int off = 32; off > 0; off >>= 1) s += __shfl_xor(s, off);
    if (s >= 0.2f * (float)N) return;   // ious.mean() >= 0.2 -> no update

    int y = label[i];
    if (y < P) {
        for (int j = 0; j < i; ++j) if (label[j] == y) return;  // first occurrence drives
        float4 r = *(const float4*)(lut + (size_t)y * DD + lane * 4);
        for (int pass = 0; pass < 2; ++pass) {
            for (int j = i; j < N; ++j) {
                if (label[j] != y) continue;
                float b = (pass == 0) ? 0.5f : ious[j];
                float a = 1.f - b;
                float4 xj = *(const float4*)(xf + (size_t)j * DD + lane * 4);
                r.x = a * r.x + b * xj.x;
                r.y = a * r.y + b * xj.y;
                r.z = a * r.z + b * xj.z;
                r.w = a * r.w + b * xj.w;
                float ss2 = r.x * r.x + r.y * r.y + r.z * r.z + r.w * r.w;
                #pragma unroll
                for (int off = 32; off > 0; off >>= 1) ss2 += __shfl_xor(ss2, off);
                float inv = 1.f / fmaxf(sqrtf(ss2), 1e-12f);
                r.x *= inv; r.y *= inv; r.z *= inv; r.w *= inv;
            }
        }
        float* dst = out_lut + (size_t)y * DD + lane * 4;
        dst[0] = r.x; dst[1] = r.y; dst[2] = r.z; dst[3] = r.w;
    } else {
        int rank = 0, U = 0;
        for (int j = 0; j < N; ++j) {
            bool u = (label[j] >= P);
            U += u ? 1 : 0;
            if (u && j < i) rank++;
        }
        int h0 = header[0];
        float4 xi = *(const float4*)(xf + (size_t)i * DD + lane * 4);
        long long p1 = ((long long)h0 + rank) % Q;
        long long p2 = ((long long)h0 + U + rank) % Q;
        float* d1 = out_cq + (size_t)p1 * DD + lane * 4;
        float* d2 = out_cq + (size_t)p2 * DD + lane * 4;
        d1[0] = xi.x; d1[1] = xi.y; d1[2] = xi.z; d1[3] = xi.w;
        d2[0] = xi.x; d2[1] = xi.y; d2[2] = xi.z; d2[3] = xi.w;
    }
}

extern "C" void kernel_launch(void* const* d_in, const int* in_sizes, int n_in,
                              void* d_out, int out_size, void* d_ws, size_t ws_size,
                              hipStream_t stream) {
    const float* inputs = (const float*)d_in[0];
    const int* label    = (const int*)d_in[1];
    const float* ious   = (const float*)d_in[2];
    const float* lut    = (const float*)d_in[3];
    const float* cq     = (const float*)d_in[4];
    const int* header   = (const int*)d_in[5];
    float* out = (float*)d_out;

    int N = in_sizes[0] / DD;      // 1024
    int P = in_sizes[3] / DD;      // 100000
    int Q = in_sizes[4] / DD;      // 50000
    int C = P + Q;                 // 150000
    int CB = (C + CPB - 1) / CPB;  // 586

    // workspace: xf | xb | pm | ps  (~6.3 MB)
    char* ws = (char*)d_ws;
    float* xf = (float*)ws;
    unsigned short* xb = (unsigned short*)(ws + (size_t)N * DD * 4);
    float* pm = (float*)(ws + (size_t)N * DD * 6);
    float* ps = pm + (size_t)CB * N;

    float* out_loss = out;
    float* out_lut  = out + 1;
    float* out_cq   = out + 1 + (size_t)P * DD;

    hipLaunchKernelGGL(prep_kernel, dim3(N), dim3(256), 0, stream, inputs, xf, xb, out_loss);
    hipLaunchKernelGGL(gemm_lse_kernel, dim3(CB, N / 512), dim3(512), 0, stream,
                       xb, lut, cq, out_lut, out_cq, pm, ps, N, P, C);
    hipLaunchKernelGGL(finalize_kernel, dim3(N), dim3(256), 0, stream,
                       pm, ps, xf, lut, label, out_loss, CB, N, P);
    hipLaunchKernelGGL(update_kernel, dim3(N), dim3(64), 0, stream,
                       xf, label, ious, lut, header, out_lut, out_cq, N, P, Q);
}